// Round 2
// baseline (161.608 us; speedup 1.0000x reference)
//
#include <hip/hip_runtime.h>

// B=4096, S=50, D=32, H=4, HD=8 ; one block per batch, everything in LDS.
#define NB 4096
constexpr float kScale = 0.35355339059327378f; // 1/sqrt(8)

// LDS layout (floats), all regions 16B-aligned:
constexpr int OFF_W  = 0;      // 3072: rawWQ|rawWK|rawWV ; WO overlays [0,1024) late
constexpr int OFF_B  = 3072;   // 128: bQ|bK|bV|bO
constexpr int OFF_MW = 3200;   // 104: 100 packed mask words + flag word at +100
constexpr int OFF_U  = 3304;   // 4800: rawQ[0,1600)|rawK[1600,3200)|rawV[3200,4800)
                               //       q overlays rawK; ctx overlays rawV
constexpr int OFF_T  = 8104;   // 1600: tmp (first-projection result, [s][32])
constexpr int OFF_K2 = 9704;   // 1600: K heads [h][s][8]
constexpr int OFF_V2 = 11304;  // 1600: V heads [h][s][8]
constexpr int S_LEN  = 12904;  // 51,616 B -> 3 blocks/CU

// One projection pass: dst = src @ W + b  (optionally scaled, head-split layout).
// Thread (d = t&31, s0 = t>>5) computes rows s0+8*ss for its column d.
// src reads are 32-lane LDS broadcasts (2 distinct addrs/wave) — conflict-free.
template<bool HEADS>
__device__ __forceinline__ void proj_pass(float* S, int src_off, int w_off, int bias_base,
                                          int dst_off, float scale, int t) {
  const int d = t & 31, s0 = t >> 5;
  const float bias = S[bias_base + d];
  float acc[7];
  #pragma unroll
  for (int ss = 0; ss < 7; ++ss) acc[ss] = bias;
  #pragma unroll
  for (int kb = 0; kb < 32; kb += 4) {
    const float w0 = S[w_off + (kb+0)*32 + d];
    const float w1 = S[w_off + (kb+1)*32 + d];
    const float w2 = S[w_off + (kb+2)*32 + d];
    const float w3 = S[w_off + (kb+3)*32 + d];
    #pragma unroll
    for (int ss = 0; ss < 7; ++ss) {
      const int s = s0 + ss*8;
      if (s < 50) {
        const float4 x = *(const float4*)&S[src_off + s*32 + kb];
        acc[ss] = fmaf(x.x, w0, fmaf(x.y, w1, fmaf(x.z, w2, fmaf(x.w, w3, acc[ss]))));
      }
    }
  }
  const int h = d >> 3, hd = d & 7;
  #pragma unroll
  for (int ss = 0; ss < 7; ++ss) {
    const int s = s0 + ss*8;
    if (s < 50) {
      const float v = acc[ss] * scale;
      if (HEADS) S[dst_off + h*400 + s*8 + hd] = v;
      else       S[dst_off + s*32 + d] = v;
    }
  }
}

__global__ __launch_bounds__(256) void mha(
    const float* __restrict__ Qg, const float* __restrict__ Kg,
    const float* __restrict__ Vg, const void* __restrict__ maskg,
    const float* __restrict__ WQg, const float* __restrict__ bQg,
    const float* __restrict__ WKg, const float* __restrict__ bKg,
    const float* __restrict__ WVg, const float* __restrict__ bVg,
    const float* __restrict__ WOg, const float* __restrict__ bOg,
    float* __restrict__ outg)
{
  __shared__ __align__(16) float S[S_LEN];
  const int t = threadIdx.x;
  const int b = blockIdx.x;

  // ---- A: stage raw W's, raw Q/K/V, biases; detect mask element width ----
  {
    const float4* wsrc0 = (const float4*)WQg;
    const float4* wsrc1 = (const float4*)WKg;
    const float4* wsrc2 = (const float4*)WVg;
    float4* dW = (float4*)&S[OFF_W];
    dW[t]       = wsrc0[t];            // 256 f4 = 1024 floats each
    dW[t + 256] = wsrc1[t];
    dW[t + 512] = wsrc2[t];

    const float4* q4 = (const float4*)Qg;
    const float4* k4 = (const float4*)Kg;
    const float4* v4 = (const float4*)Vg;
    float4* dU = (float4*)&S[OFF_U];
    #pragma unroll
    for (int it = 0; it < 5; ++it) {
      int idx = t + it*256;
      if (idx < 1200) {
        int m = idx / 400, e = idx - m*400;
        const float4* src = (m == 0) ? q4 : (m == 1) ? k4 : v4;
        dU[m*400 + e] = src[b*400 + e];
      }
    }
    if      (t < 32)  S[OFF_B + t] = bQg[t];
    else if (t < 64)  S[OFF_B + t] = bKg[t - 32];
    else if (t < 96)  S[OFF_B + t] = bVg[t - 64];
    else if (t < 128) S[OFF_B + t] = bOg[t - 96];

    if (t < 64) {   // wave 0 exactly: detect int32 vs byte mask
      const unsigned w = ((const unsigned*)maskg)[t];
      const unsigned long long ball = __ballot(w > 1u);
      if (t == 0) ((unsigned*)S)[OFF_MW + 100] = (ball != 0ull) ? 1u : 0u;
    }
  }
  __syncthreads();

  // ---- B: bit-pack mask (t<100) + first projection of K ----
  {
    const unsigned flag = ((const unsigned*)S)[OFF_MW + 100];
    if (t < 100) {
      const int i = t >> 1, half = t & 1;
      const int base = b*2500 + i*50 + half*32;
      const int cnt = half ? 18 : 32;
      unsigned w = 0;
      if (flag) {
        const unsigned char* mp = (const unsigned char*)maskg + base;
        for (int e = 0; e < cnt; ++e) w |= (mp[e] != 0) ? (1u << e) : 0u;
      } else {
        const int* mp = (const int*)maskg + base;
        for (int e = 0; e < cnt; ++e) w |= (mp[e] != 0) ? (1u << e) : 0u;
      }
      ((unsigned*)S)[OFF_MW + t] = w;
    }
  }
  proj_pass<false>(S, OFF_U + 1600, OFF_W + 1024, OFF_B + 32, OFF_T, 1.f, t);
  __syncthreads();
  // ---- C: second projection of K -> head layout ----
  proj_pass<true>(S, OFF_T, OFF_W + 1024, OFF_B + 32, OFF_K2, 1.f, t);
  __syncthreads();
  // ---- D: first projection of V ----
  proj_pass<false>(S, OFF_U + 3200, OFF_W + 2048, OFF_B + 64, OFF_T, 1.f, t);
  __syncthreads();
  // ---- E: second projection of V ----
  proj_pass<true>(S, OFF_T, OFF_W + 2048, OFF_B + 64, OFF_V2, 1.f, t);
  __syncthreads();
  // ---- F: first projection of Q ----
  proj_pass<false>(S, OFF_U, OFF_W, OFF_B, OFF_T, 1.f, t);
  __syncthreads();
  // ---- G: second projection of Q -> q (pre-scaled) into dead rawK region ----
  proj_pass<true>(S, OFF_T, OFF_W, OFF_B, OFF_U + 1600, kScale, t);
  __syncthreads();

  // ---- H: overlay WO into S[0,1024) (weights dead) + attention ----
  ((float4*)S)[t] = ((const float4*)WOg)[t];   // 256 f4 = 1024 floats
  if (t < 200) {
    const int h = t / 50, i = t - h*50;
    const float* qh = &S[OFF_U + 1600 + h*400];
    const float* kh = &S[OFF_K2 + h*400];
    const float* vh = &S[OFF_V2 + h*400];
    float qr[8];
    {
      const float4 q0 = *(const float4*)&qh[i*8];
      const float4 q1 = *(const float4*)&qh[i*8 + 4];
      qr[0]=q0.x; qr[1]=q0.y; qr[2]=q0.z; qr[3]=q0.w;
      qr[4]=q1.x; qr[5]=q1.y; qr[6]=q1.z; qr[7]=q1.w;
    }
    const unsigned mw0 = ((const unsigned*)S)[OFF_MW + i*2];
    const unsigned mw1 = ((const unsigned*)S)[OFF_MW + i*2 + 1];
    float sb[50];
    float mx = -__builtin_inff();
    #pragma unroll
    for (int j = 0; j < 50; ++j) {
      const float4 k0 = *(const float4*)&kh[j*8];
      const float4 k1 = *(const float4*)&kh[j*8 + 4];
      float s =        qr[0]*k0.x;
      s = fmaf(qr[1], k0.y, s);
      s = fmaf(qr[2], k0.z, s);
      s = fmaf(qr[3], k0.w, s);
      s = fmaf(qr[4], k1.x, s);
      s = fmaf(qr[5], k1.y, s);
      s = fmaf(qr[6], k1.z, s);
      s = fmaf(qr[7], k1.w, s);
      const unsigned bit = (j < 32) ? ((mw0 >> j) & 1u) : ((mw1 >> (j-32)) & 1u);
      s = bit ? -__builtin_inff() : s;
      sb[j] = s;
      mx = fmaxf(mx, s);
    }
    float sum = 0.f;
    float acc[8] = {0,0,0,0,0,0,0,0};
    #pragma unroll
    for (int j = 0; j < 50; ++j) {
      const float p = __expf(sb[j] - mx);
      sum += p;
      const float4 v0 = *(const float4*)&vh[j*8];
      const float4 v1 = *(const float4*)&vh[j*8 + 4];
      acc[0] = fmaf(p, v0.x, acc[0]);
      acc[1] = fmaf(p, v0.y, acc[1]);
      acc[2] = fmaf(p, v0.z, acc[2]);
      acc[3] = fmaf(p, v0.w, acc[3]);
      acc[4] = fmaf(p, v1.x, acc[4]);
      acc[5] = fmaf(p, v1.y, acc[5]);
      acc[6] = fmaf(p, v1.z, acc[6]);
      acc[7] = fmaf(p, v1.w, acc[7]);
    }
    const float inv = 1.f / sum;
    float4 o0 = make_float4(acc[0]*inv, acc[1]*inv, acc[2]*inv, acc[3]*inv);
    float4 o1 = make_float4(acc[4]*inv, acc[5]*inv, acc[6]*inv, acc[7]*inv);
    *(float4*)&S[OFF_U + 3200 + h*400 + i*8]     = o0;   // ctx into dead rawV region
    *(float4*)&S[OFF_U + 3200 + h*400 + i*8 + 4] = o1;
  }
  __syncthreads();

  // ---- J: out = rawQ + ctx @ WO + bO ----
  {
    const int d = t & 31, s0 = t >> 5;
    float acc[7];
    #pragma unroll
    for (int ss = 0; ss < 7; ++ss) acc[ss] = S[OFF_B + 96 + d];
    #pragma unroll
    for (int kb = 0; kb < 32; kb += 4) {
      const int h = kb >> 3, k4 = kb & 4;
      const float w0 = S[(kb+0)*32 + d];
      const float w1 = S[(kb+1)*32 + d];
      const float w2 = S[(kb+2)*32 + d];
      const float w3 = S[(kb+3)*32 + d];
      #pragma unroll
      for (int ss = 0; ss < 7; ++ss) {
        const int s = s0 + ss*8;
        if (s < 50) {
          const float4 x = *(const float4*)&S[OFF_U + 3200 + h*400 + s*8 + k4];
          acc[ss] = fmaf(x.x, w0, fmaf(x.y, w1, fmaf(x.z, w2, fmaf(x.w, w3, acc[ss]))));
        }
      }
    }
    #pragma unroll
    for (int ss = 0; ss < 7; ++ss) {
      const int s = s0 + ss*8;
      if (s < 50) outg[b*1600 + s*32 + d] = S[OFF_U + s*32 + d] + acc[ss];
    }
  }
}

extern "C" void kernel_launch(void* const* d_in, const int* in_sizes, int n_in,
                              void* d_out, int out_size, void* d_ws, size_t ws_size,
                              hipStream_t stream) {
  const float* Q  = (const float*)d_in[0];
  const float* K  = (const float*)d_in[1];
  const float* V  = (const float*)d_in[2];
  const void*  M  = d_in[3];
  const float* WQ = (const float*)d_in[4];
  const float* bQ = (const float*)d_in[5];
  const float* WK = (const float*)d_in[6];
  const float* bK = (const float*)d_in[7];
  const float* WV = (const float*)d_in[8];
  const float* bV = (const float*)d_in[9];
  const float* WO = (const float*)d_in[10];
  const float* bO = (const float*)d_in[11];
  float* out = (float*)d_out;
  (void)d_ws; (void)ws_size; (void)in_sizes; (void)n_in; (void)out_size;

  hipLaunchKernelGGL(mha, dim3(NB), dim3(256), 0, stream,
                     Q, K, V, M, WQ, bQ, WK, bK, WV, bV, WO, bO, out);
}